// Round 1
// 627.853 us; speedup vs baseline: 1.0258x; 1.0258x over previous
//
#include <hip/hip_runtime.h>

#define PLACEHOLDER (-1)

// Problem shape: B=256 seqs, K=8 drafts/seq, V=50257 vocab, T=B*K=2048 rows.
//
// Single fused kernel, B blocks x 1024 threads:
//   Phase 0 (wave 0): start offset (exact int sum over num_draft_tokens),
//                     accept run via per-lane gather + __ballot, all count
//                     outputs + out row (except recovered slot).
//   Phase A: barrier-free tile sums of adjusted=max(t-d,0) and t into a
//            [NT][16] LDS matrix; one barrier; tile sums rebuilt in the
//            SAME w=0..15 serial order as the previous kernel (bit-exact).
//   Phase B: rescan only the crossing tile (identical structure to prior
//            kernel -> identical float association -> identical tokens).

#define K2_BLOCK 1024
#define K2_C     4
#define K2_TILE  (K2_BLOCK * K2_C)   // 4096
#define MAX_TILES 64

__global__ __launch_bounds__(K2_BLOCK)
void fused_rejection(const int* __restrict__ draft_token_ids,
                     const int* __restrict__ num_draft_tokens,
                     const float* __restrict__ draft_probs,
                     const float* __restrict__ target_probs,
                     const int* __restrict__ bonus_token_ids,
                     const float* __restrict__ uniform_samples,
                     const float* __restrict__ resample_uniforms,
                     int* __restrict__ out,              // B*(K+1)
                     int* __restrict__ num_accepted,     // B
                     int* __restrict__ accepted_counts,  // B
                     int* __restrict__ recovered_counts, // B
                     int* __restrict__ bonus_counts,     // B
                     int B, int K, int V, int T)
{
    const int b    = blockIdx.x;
    const int tid  = threadIdx.x;
    const int lane = tid & 63;
    const int wave = tid >> 6;                  // 0..15

    __shared__ float s_wa[MAX_TILES * 16];
    __shared__ float s_wt[MAX_TILES * 16];
    __shared__ float s_adj[MAX_TILES];
    __shared__ float s_t[MAX_TILES];
    __shared__ float s_w[16];
    __shared__ int   s_cnt[16];
    __shared__ int   s_info[2];                 // {rej_row, slot or -1}

    // ---- Phase 0: accept run for sequence b (wave 0 only) ----
    if (wave == 0) {
        // Exclusive-prefix start = sum_{i<b} n[i]; exact integer arithmetic.
        int acc = 0, nb = 0;
        for (int i = lane; i < B; i += 64) {
            const int v = num_draft_tokens[i];
            if (i < b)  acc += v;
            if (i == b) nb  = v;
        }
        #pragma unroll
        for (int off = 32; off; off >>= 1) {
            acc += __shfl_down(acc, off, 64);
            nb  += __shfl_down(nb,  off, 64);
        }
        const int start = __shfl(acc, 0, 64);
        const int n     = __shfl(nb,  0, 64);

        // One independent gather per lane (lanes 0..K-1): tok, pd, pt, u.
        int  tok = 0;
        bool accept_lane = false;
        if (lane < K && lane < n) {
            const int r = start + lane;
            tok = draft_token_ids[r];
            const long long ro = (long long)r * (long long)V;
            const float d = fmaxf(draft_probs[ro + tok], 1e-10f);
            const float t = target_probs[ro + tok];
            const float u = uniform_samples[r];
            accept_lane = (u < fminf(1.0f, t / d));
        }
        const unsigned long long mask  = __ballot(accept_lane);
        const unsigned long long valid = (n >= 64) ? ~0ull : ((1ull << n) - 1ull);
        const unsigned long long m2    = (~mask) & valid;
        const int  num_acc = m2 ? (int)(__ffsll(m2) - 1) : n;   // leading run
        const bool all_acc = (num_acc == n);

        // Out row: lane p writes slot p (K+1 slots). Recovered slot is
        // PLACEHOLDER for now; phase B overwrites it when !all_acc.
        if (lane <= K) {
            int val = PLACEHOLDER;
            if (lane < num_acc)                  val = tok;
            else if (lane == num_acc && all_acc) val = bonus_token_ids[b];
            out[b * (K + 1) + lane] = val;
        }
        if (lane == 0) {
            num_accepted[b]     = num_acc + 1;
            accepted_counts[b]  = num_acc;
            recovered_counts[b] = all_acc ? 0 : 1;
            bonus_counts[b]     = all_acc ? 1 : 0;

            int rej_pos = num_acc; if (rej_pos > K - 1) rej_pos = K - 1;
            int rej_row = start + rej_pos;
            if (rej_row > T - 1) rej_row = T - 1;
            if (rej_row < 0)     rej_row = 0;
            s_info[0] = rej_row;
            s_info[1] = all_acc ? -1 : num_acc;
        }
    }
    __syncthreads();

    const int slot = s_info[1];
    if (slot < 0) return;                       // uniform across block
    const int row  = s_info[0];

    const float* __restrict__ trow = target_probs + (long long)row * (long long)V;
    const float* __restrict__ drow = draft_probs  + (long long)row * (long long)V;
    const float u = resample_uniforms[b];
    const int NT = (V + K2_TILE - 1) / K2_TILE; // 13 for V=50257

    // ---- Phase A: per-tile sums, NO barriers inside the stream loop ----
    for (int t = 0; t < NT; t++) {
        const int base = t * K2_TILE;
        float ta[K2_C], da[K2_C];
        #pragma unroll
        for (int c = 0; c < K2_C; c++) {
            const int idx = base + c * K2_BLOCK + tid;
            const bool ok = idx < V;
            ta[c] = ok ? trow[idx] : 0.0f;
            da[c] = ok ? drow[idx] : 0.0f;
        }
        float aa = 0.0f, at = 0.0f;
        #pragma unroll
        for (int c = 0; c < K2_C; c++) {
            aa += fmaxf(ta[c] - da[c], 0.0f);   // same per-thread association
            at += ta[c];
        }
        #pragma unroll
        for (int off = 32; off; off >>= 1) {    // same shfl tree as before
            aa += __shfl_down(aa, off, 64);
            at += __shfl_down(at, off, 64);
        }
        if (lane == 0) {
            s_wa[t * 16 + wave] = aa;
            s_wt[t * 16 + wave] = at;
        }
    }
    __syncthreads();
    // Rebuild tile sums in the identical w=0..15 serial order (bit-exact
    // with the previous kernel's tid==0 loop).
    if (tid < NT) {
        float sa = 0.0f, st = 0.0f;
        for (int w = 0; w < 16; w++) {
            sa += s_wa[tid * 16 + w];
            st += s_wt[tid * 16 + w];
        }
        s_adj[tid] = sa;
        s_t[tid]   = st;
    }
    __syncthreads();

    // ---- total + threshold + crossing tile (redundant per thread) ----
    float s = 0.0f;
    for (int t = 0; t < NT; t++) s += s_adj[t];
    const bool  use_adj = (s > 1e-10f);
    const float thresh  = use_adj ? u * s : u;
    const float* sums   = use_adj ? s_adj : s_t;

    int tc = -1; float base = 0.0f;
    for (int t = 0; t < NT; t++) {
        const float ns = base + sums[t];
        if (ns >= thresh) { tc = t; break; }
        base = ns;
    }

    if (tc < 0) {                               // thresh beyond total: count=V
        if (tid == 0) out[b * (K + 1) + slot] = V - 1;
        return;
    }

    // ---- Phase B: rescan only the crossing tile (structure unchanged) ----
    int cnt = 0;
    float run = base;
    for (int c = 0; c < K2_C; c++) {
        const int idx = tc * K2_TILE + c * K2_BLOCK + tid;
        const bool ok = idx < V;
        float v = 0.0f;
        if (ok) {
            const float tv = trow[idx];
            v = use_adj ? fmaxf(tv - drow[idx], 0.0f) : tv;
        }
        // inclusive scan within wave
        float x = v;
        #pragma unroll
        for (int off = 1; off < 64; off <<= 1) {
            const float y = __shfl_up(x, off, 64);
            if (lane >= off) x += y;
        }
        if (lane == 63) s_w[wave] = x;
        __syncthreads();
        float wbase = 0.0f, chunk = 0.0f;
        for (int w = 0; w < 16; w++) {
            const float ws = s_w[w];
            if (w < wave) wbase += ws;
            chunk += ws;
        }
        const float incl = run + wbase + x;
        if (ok && incl < thresh) cnt++;
        run += chunk;
        __syncthreads();
    }
    #pragma unroll
    for (int off = 32; off; off >>= 1) cnt += __shfl_down(cnt, off, 64);
    if (lane == 0) s_cnt[wave] = cnt;
    __syncthreads();
    if (tid == 0) {
        int tot = 0;
        for (int w = 0; w < 16; w++) tot += s_cnt[w];
        int recovered = tc * K2_TILE + tot;
        if (recovered > V - 1) recovered = V - 1;
        out[b * (K + 1) + slot] = recovered;
    }
}

// ---------------------------------------------------------------------------
extern "C" void kernel_launch(void* const* d_in, const int* in_sizes, int n_in,
                              void* d_out, int out_size, void* d_ws, size_t ws_size,
                              hipStream_t stream)
{
    const int*   draft_token_ids   = (const int*)  d_in[0];
    const int*   num_draft_tokens  = (const int*)  d_in[1];
    const float* draft_probs       = (const float*)d_in[2];
    const float* target_probs      = (const float*)d_in[3];
    const int*   bonus_token_ids   = (const int*)  d_in[4];
    const float* uniform_samples   = (const float*)d_in[5];
    const float* resample_uniforms = (const float*)d_in[6];

    const int T = in_sizes[0];
    const int B = in_sizes[1];
    const int V = (int)((long long)in_sizes[2] / (long long)T);
    const int K = T / B;

    int* out              = (int*)d_out;
    int* num_accepted     = out + B * (K + 1);
    int* accepted_counts  = num_accepted + B;
    int* recovered_counts = accepted_counts + B;
    int* bonus_counts     = recovered_counts + B;

    fused_rejection<<<B, K2_BLOCK, 0, stream>>>(
        draft_token_ids, num_draft_tokens, draft_probs, target_probs,
        bonus_token_ids, uniform_samples, resample_uniforms,
        out, num_accepted, accepted_counts, recovered_counts, bonus_counts,
        B, K, V, T);
}